// Round 6
// baseline (120.304 us; speedup 1.0000x reference)
//
#include <hip/hip_runtime.h>
#include <math.h>

#define NT 1024
#define PW 66      // padded LDS row stride
#define RR 52      // LDS buffer rows (52 X rows / 50 r rows / 48 v rows + ring)

// Pin a value into an AGPR (unified file) so arch VGPRs stay free for hot data.
#define AW(arr, idx, val) asm("v_accvgpr_write_b32 %0, %1" : "=a"(arr[idx]) : "v"(val))
#define AR(dst, arr, idx) asm("v_accvgpr_read_b32 %0, %1" : "=v"(dst) : "a"(arr[idx]))

// max over the 4 lanes of a quad via DPP (pure VALU, no LDS pipe):
// xor1 = quad_perm[1,0,3,2] = 0xB1 ; xor2 = quad_perm[2,3,0,1] = 0x4E
static __device__ __forceinline__ float quad_max(float m) {
    int t = __builtin_amdgcn_update_dpp(__float_as_int(m), __float_as_int(m), 0xB1, 0xF, 0xF, false);
    m = fmaxf(m, __int_as_float(t));
    t = __builtin_amdgcn_update_dpp(__float_as_int(m), __float_as_int(m), 0x4E, 0xF, 0xF, false);
    return fmaxf(m, __int_as_float(t));
}

// Two launches: chunk<15,FIRST> then chunk<14,LAST>. 256 blocks, block = half image
// (32 core rows + 16-row internal halo). Wave = 16 pixel-slots x 4 channel-groups:
// lane: g = lane&3 (channels 4g..4g+3), p = lane>>2, col c=(wid&3)*16+p,
// rows band*12..band*12+11 (band = wid>>2). Channel-max = in-lane + 2 DPP steps.
template<int NIT, bool FIRST, bool LAST>
__global__ __launch_bounds__(NT, 4)
void vin_chunk(const float* __restrict__ layout,
               const float* __restrict__ heatmap,
               const float* __restrict__ h_w,
               const float* __restrict__ h_b,
               const float* __restrict__ r_w,
               const float* __restrict__ q_w,
               const float* __restrict__ w,
               const float* __restrict__ fc_w,
               const int* __restrict__ S1,
               const int* __restrict__ S2,
               float* __restrict__ vg,
               float* __restrict__ out)
{
    __shared__ float rh[28];
    __shared__ float r_s[RR * PW];   // X0, then r   (r_s row M <-> image row vlo-1+M)
    __shared__ float va[RR * PW];    // X1, then v ping (v row L <-> image row vlo+L-1)
    __shared__ float vb[RR * PW];    // X2, then v pong

    const int b2   = blockIdx.x;
    const int b    = b2 >> 1;
    const int half = b2 & 1;
    const int vlo  = half ? 16 : 0;
    const int tid  = threadIdx.x;

    // B0: zero everything (borders must be 0)
    for (int i = tid; i < RR * PW; i += NT) { r_s[i] = 0.f; va[i] = 0.f; vb[i] = 0.f; }
    __syncthreads();

    // collapse 150-ch h-conv + 1x1 r-conv into 28 coeffs (32 threads per coeff)
    if (tid < 896) {
        const int coeff = tid >> 5, j = tid & 31;
        float s = 0.f;
        for (int c = j; c < 150; c += 32)
            s += r_w[c] * ((coeff < 27) ? h_w[c * 27 + coeff] : h_b[c]);
        s += __shfl_xor(s, 1, 32);  s += __shfl_xor(s, 2, 32);
        s += __shfl_xor(s, 4, 32);  s += __shfl_xor(s, 8, 32);
        s += __shfl_xor(s, 16, 32);
        if (j == 0) rh[coeff] = s;
    }
    // stage X rows M=0..51 <-> image rows vlo-2..vlo+49 (zero OOB kept from memset)
    const float* X0 = layout  + (size_t)b * 2 * 4096;
    const float* X1 = X0 + 4096;
    const float* X2 = heatmap + (size_t)b * 4096;
    for (int i = tid; i < RR * 64; i += NT) {
        const int M = i >> 6, col = i & 63;
        const int ir = vlo - 2 + M;
        if (ir >= 0 && ir < 64) {
            const int s = ir * 64 + col, d = M * PW + col + 1;
            r_s[d] = X0[s]; va[d] = X1[s]; vb[d] = X2[s];
        }
    }
    __syncthreads();  // B1: X + rh ready

    // r (rows 0..49, cols 0..63) into registers; window top X-row == dest r-row
    float rv[4];
    int   rpx[4];
    #pragma unroll
    for (int k2 = 0; k2 < 4; ++k2) {
        const int i = tid + k2 * NT;
        rpx[k2] = -1;
        if (i < 50 * 64) {
            const int row = i >> 6, col = i & 63;
            float acc = rh[27];
            #pragma unroll
            for (int dy = 0; dy < 3; ++dy)
                #pragma unroll
                for (int dx = 0; dx < 3; ++dx) {
                    const int idx = (row + dy) * PW + col + dx;
                    acc = fmaf(rh[0 * 9 + dy * 3 + dx], r_s[idx], acc);
                    acc = fmaf(rh[1 * 9 + dy * 3 + dx], va[idx],  acc);
                    acc = fmaf(rh[2 * 9 + dy * 3 + dx], vb[idx],  acc);
                }
            const int ir = vlo - 1 + row;
            rv[k2]  = (ir >= 0 && ir < 64) ? acc : 0.f;  // true zero padding
            rpx[k2] = row * PW + col + 1;
        }
    }
    __syncthreads();  // B2: X consumed

    // overwrite: r -> r_s, re-zero v buffers
    for (int i = tid; i < RR * PW; i += NT) { va[i] = 0.f; vb[i] = 0.f; }
    #pragma unroll
    for (int k2 = 0; k2 < 4; ++k2) if (rpx[k2] >= 0) r_s[rpx[k2]] = rv[k2];
    __syncthreads();  // B3: r ready, v buffers zero

    // per-lane geometry (quad-based channel groups)
    const int wid  = tid >> 6, lane = tid & 63;
    const int g    = lane & 3;       // channel group: channels 4g..4g+3
    const int p    = lane >> 2;      // pixel slot 0..15
    const int c    = (wid & 3) * 16 + p;
    const int band = wid >> 2;
    const int rb0  = band * 12;      // conv-window top LDS row for j=0

    // stage v (non-FIRST) rows 1..48 <- vg image rows vlo..vlo+47
    if (!FIRST) {
        for (int i = tid; i < 48 * 64; i += NT) {
            const int L = (i >> 6) + 1, col = i & 63;
            va[L * PW + col + 1] = vg[b * 4096 + (vlo + L - 1) * 64 + col];
        }
    }

    // rq[cc*12+j] = conv3x3(r, q_w[4g+cc]) at (row 1+rb0+j, col c) -> pinned to AGPRs
    float wq[36];
    #pragma unroll
    for (int t = 0; t < 36; ++t) wq[t] = q_w[g * 36 + t];

    float rqa[48];   // lives in AGPRs via AW/AR
    {
        const float* rw = r_s + rb0 * PW + c;
        float a0[3], a1[3], a2[3];
        #pragma unroll
        for (int d = 0; d < 3; ++d) { a0[d] = rw[d]; a1[d] = rw[PW + d]; }
        #pragma unroll
        for (int j = 0; j < 12; ++j) {
            #pragma unroll
            for (int d = 0; d < 3; ++d) a2[d] = rw[(j + 2) * PW + d];
            float q4[4];
            #pragma unroll
            for (int cc = 0; cc < 4; ++cc) {
                float a = 0.f;
                #pragma unroll
                for (int d = 0; d < 3; ++d) {
                    a = fmaf(wq[cc * 9 + d],     a0[d], a);
                    a = fmaf(wq[cc * 9 + 3 + d], a1[d], a);
                    a = fmaf(wq[cc * 9 + 6 + d], a2[d], a);
                }
                q4[cc] = a;
                AW(rqa, cc * 12 + j, a);
            }
            if (FIRST) {
                float m = fmaxf(fmaxf(q4[0], q4[1]), fmaxf(q4[2], q4[3]));
                m = quad_max(m);
                if (g == 0) va[(1 + rb0 + j) * PW + c + 1] = m;
            }
            #pragma unroll
            for (int d = 0; d < 3; ++d) { a0[d] = a1[d]; a1[d] = a2[d]; }
        }
    }

    float wv[36];
    #pragma unroll
    for (int t = 0; t < 36; ++t) wv[t] = w[g * 36 + t];
    __syncthreads();  // B4: v0 / staged v ready

    // NIT sweeps
    float* vcur = va;
    float* vnxt = vb;
    #pragma unroll 1
    for (int it = 0; it < NIT; ++it) {
        const float* vw = vcur + rb0 * PW + c;
        float a0[3], a1[3], a2[3];
        #pragma unroll
        for (int d = 0; d < 3; ++d) { a0[d] = vw[d]; a1[d] = vw[PW + d]; }
        #pragma unroll
        for (int j = 0; j < 12; ++j) {
            #pragma unroll
            for (int d = 0; d < 3; ++d) a2[d] = vw[(j + 2) * PW + d];
            float q0, q1, q2, q3;
            AR(q0, rqa, 0 * 12 + j);
            AR(q1, rqa, 1 * 12 + j);
            AR(q2, rqa, 2 * 12 + j);
            AR(q3, rqa, 3 * 12 + j);
            #pragma unroll
            for (int d = 0; d < 3; ++d) {
                q0 = fmaf(wv[0 + d],  a0[d], q0); q0 = fmaf(wv[3 + d],  a1[d], q0); q0 = fmaf(wv[6 + d],  a2[d], q0);
                q1 = fmaf(wv[9 + d],  a0[d], q1); q1 = fmaf(wv[12 + d], a1[d], q1); q1 = fmaf(wv[15 + d], a2[d], q1);
                q2 = fmaf(wv[18 + d], a0[d], q2); q2 = fmaf(wv[21 + d], a1[d], q2); q2 = fmaf(wv[24 + d], a2[d], q2);
                q3 = fmaf(wv[27 + d], a0[d], q3); q3 = fmaf(wv[30 + d], a1[d], q3); q3 = fmaf(wv[33 + d], a2[d], q3);
            }
            float m = fmaxf(fmaxf(q0, q1), fmaxf(q2, q3));
            m = quad_max(m);
            if (g == 0) vnxt[(1 + rb0 + j) * PW + c + 1] = m;
            #pragma unroll
            for (int d = 0; d < 3; ++d) { a0[d] = a1[d]; a1[d] = a2[d]; }
        }
        __syncthreads();
        float* t = vcur; vcur = vnxt; vnxt = t;
    }

    // writeback core rows (image half*32 .. half*32+31; L = ir - vlo + 1)
    if (!LAST) {
        for (int i = tid; i < 32 * 64; i += NT) {
            const int ir = half * 32 + (i >> 6), col = i & 63;
            vg[b * 4096 + ir * 64 + col] = vcur[(ir - vlo + 1) * PW + col + 1];
        }
    } else {
        float* out_v = out + 1024 + (size_t)b * 4096;
        for (int i = tid; i < 32 * 64; i += NT) {
            const int ir = half * 32 + (i >> 6), col = i & 63;
            out_v[ir * 64 + col] = vcur[(ir - vlo + 1) * PW + col + 1];
        }
    }
    if (FIRST) {
        float* out_r = out + 1024 + (size_t)128 * 4096 + (size_t)b * 4096;
        float* out_h = out + 1024 + (size_t)256 * 4096 + (size_t)b * 4096;
        for (int i = tid; i < 32 * 64; i += NT) {
            const int ir = half * 32 + (i >> 6), col = i & 63;
            out_r[ir * 64 + col] = r_s[(ir - vlo + 1) * PW + col + 1];
            out_h[ir * 64 + col] = X2[ir * 64 + col];
        }
    }

    if (LAST) {
        const int s1 = S1[b], s2 = S2[b];
        if ((s1 >> 5) == half && tid == 0) {
            float q16[16];
            #pragma unroll
            for (int o = 0; o < 16; ++o) {
                float acc = 0.f;
                #pragma unroll
                for (int dy = 0; dy < 3; ++dy)
                    #pragma unroll
                    for (int dx = 0; dx < 3; ++dx) {
                        const int li = (s1 + dy - vlo) * PW + s2 + dx;
                        acc = fmaf(q_w[o * 9 + dy * 3 + dx], r_s[li], acc);
                        acc = fmaf(w[o * 9 + dy * 3 + dx],  vcur[li], acc);
                    }
                q16[o] = acc;
            }
            float lg[4];
            #pragma unroll
            for (int j = 0; j < 4; ++j) {
                float a = 0.f;
                #pragma unroll
                for (int o = 0; o < 16; ++o) a = fmaf(fc_w[j * 16 + o], q16[o], a);
                lg[j] = a;
            }
            const float m  = fmaxf(fmaxf(lg[0], lg[1]), fmaxf(lg[2], lg[3]));
            const float e0 = expf(lg[0] - m), e1 = expf(lg[1] - m);
            const float e2 = expf(lg[2] - m), e3 = expf(lg[3] - m);
            const float s  = e0 + e1 + e2 + e3;
            out[b * 4 + 0] = lg[0]; out[b * 4 + 1] = lg[1];
            out[b * 4 + 2] = lg[2]; out[b * 4 + 3] = lg[3];
            out[512 + b * 4 + 0] = e0 / s; out[512 + b * 4 + 1] = e1 / s;
            out[512 + b * 4 + 2] = e2 / s; out[512 + b * 4 + 3] = e3 / s;
        }
    }
}

extern "C" void kernel_launch(void* const* d_in, const int* in_sizes, int n_in,
                              void* d_out, int out_size, void* d_ws, size_t ws_size,
                              hipStream_t stream) {
    const float* layout  = (const float*)d_in[0];
    const float* heatmap = (const float*)d_in[1];
    const float* h_w     = (const float*)d_in[2];
    const float* h_b     = (const float*)d_in[3];
    const float* r_w     = (const float*)d_in[4];
    const float* q_w     = (const float*)d_in[5];
    const float* w       = (const float*)d_in[6];
    const float* fc_w    = (const float*)d_in[7];
    const int*   S1      = (const int*)d_in[8];
    const int*   S2      = (const int*)d_in[9];
    float* out = (float*)d_out;
    float* vg  = (float*)d_ws;   // 128*4096 f32 = 2 MB

    hipLaunchKernelGGL((vin_chunk<15, true,  false>), dim3(256), dim3(NT), 0, stream,
                       layout, heatmap, h_w, h_b, r_w, q_w, w, fc_w, S1, S2, vg, out);
    hipLaunchKernelGGL((vin_chunk<14, false, true>),  dim3(256), dim3(NT), 0, stream,
                       layout, heatmap, h_w, h_b, r_w, q_w, w, fc_w, S1, S2, vg, out);
}

// Round 7
// 116.646 us; speedup vs baseline: 1.0314x; 1.0314x over previous
//
#include <hip/hip_runtime.h>
#include <math.h>

#define NT 1024
#define PW 66      // padded LDS row stride
#define RR 52      // LDS buffer rows (52 X rows / 50 r rows / 48 v rows + ring)

// Two launches: chunk<15,FIRST> then chunk<14,LAST>. 256 blocks (1 per CU),
// block = half image (32 core rows + 16-row internal halo).
// Wave = 16 pixel-cols x 4 channel-groups: lane: g = lane>>4 (channels 4g..4g+3),
// p = lane&15, col c=(wid&3)*16+p, rows band*12..band*12+11 (band = wid>>2).
// NOTE: __launch_bounds__ 2nd arg = min BLOCKS/CU. Grid==256==#CUs, so demand
// only 1 resident block -> 128-VGPR budget -> wv/rq stay in arch VGPRs
// (at (NT,4) the compiler capped at 64 VGPRs and shuttled rq/wv via AGPRs).
template<int NIT, bool FIRST, bool LAST>
__global__ __launch_bounds__(NT, 1)
void vin_chunk(const float* __restrict__ layout,
               const float* __restrict__ heatmap,
               const float* __restrict__ h_w,
               const float* __restrict__ h_b,
               const float* __restrict__ r_w,
               const float* __restrict__ q_w,
               const float* __restrict__ w,
               const float* __restrict__ fc_w,
               const int* __restrict__ S1,
               const int* __restrict__ S2,
               float* __restrict__ vg,
               float* __restrict__ out)
{
    __shared__ float rh[28];
    __shared__ float r_s[RR * PW];   // X0, then r   (r_s row M <-> image row vlo-1+M)
    __shared__ float va[RR * PW];    // X1, then v ping (v row L <-> image row vlo+L-1)
    __shared__ float vb[RR * PW];    // X2, then v pong

    const int b2   = blockIdx.x;
    const int b    = b2 >> 1;
    const int half = b2 & 1;
    const int vlo  = half ? 16 : 0;
    const int tid  = threadIdx.x;

    // B0: zero everything (borders must be 0)
    for (int i = tid; i < RR * PW; i += NT) { r_s[i] = 0.f; va[i] = 0.f; vb[i] = 0.f; }
    __syncthreads();

    // collapse 150-ch h-conv + 1x1 r-conv into 28 coeffs (32 threads per coeff)
    if (tid < 896) {
        const int coeff = tid >> 5, j = tid & 31;
        float s = 0.f;
        for (int c = j; c < 150; c += 32)
            s += r_w[c] * ((coeff < 27) ? h_w[c * 27 + coeff] : h_b[c]);
        s += __shfl_xor(s, 1, 32);  s += __shfl_xor(s, 2, 32);
        s += __shfl_xor(s, 4, 32);  s += __shfl_xor(s, 8, 32);
        s += __shfl_xor(s, 16, 32);
        if (j == 0) rh[coeff] = s;
    }
    // stage X rows M=0..51 <-> image rows vlo-2..vlo+49 (zero OOB kept from memset)
    const float* X0 = layout  + (size_t)b * 2 * 4096;
    const float* X1 = X0 + 4096;
    const float* X2 = heatmap + (size_t)b * 4096;
    for (int i = tid; i < RR * 64; i += NT) {
        const int M = i >> 6, col = i & 63;
        const int ir = vlo - 2 + M;
        if (ir >= 0 && ir < 64) {
            const int s = ir * 64 + col, d = M * PW + col + 1;
            r_s[d] = X0[s]; va[d] = X1[s]; vb[d] = X2[s];
        }
    }
    __syncthreads();  // B1: X + rh ready

    // r (rows 0..49, cols 0..63) into registers; window top X-row == dest r-row
    float rv[4];
    int   rpx[4];
    #pragma unroll
    for (int k2 = 0; k2 < 4; ++k2) {
        const int i = tid + k2 * NT;
        rpx[k2] = -1;
        if (i < 50 * 64) {
            const int row = i >> 6, col = i & 63;
            float acc = rh[27];
            #pragma unroll
            for (int dy = 0; dy < 3; ++dy)
                #pragma unroll
                for (int dx = 0; dx < 3; ++dx) {
                    const int idx = (row + dy) * PW + col + dx;
                    acc = fmaf(rh[0 * 9 + dy * 3 + dx], r_s[idx], acc);
                    acc = fmaf(rh[1 * 9 + dy * 3 + dx], va[idx],  acc);
                    acc = fmaf(rh[2 * 9 + dy * 3 + dx], vb[idx],  acc);
                }
            const int ir = vlo - 1 + row;
            rv[k2]  = (ir >= 0 && ir < 64) ? acc : 0.f;  // true zero padding
            rpx[k2] = row * PW + col + 1;
        }
    }
    __syncthreads();  // B2: X consumed

    // overwrite: r -> r_s, re-zero v buffers
    for (int i = tid; i < RR * PW; i += NT) { va[i] = 0.f; vb[i] = 0.f; }
    #pragma unroll
    for (int k2 = 0; k2 < 4; ++k2) if (rpx[k2] >= 0) r_s[rpx[k2]] = rv[k2];
    __syncthreads();  // B3: r ready, v buffers zero

    // per-lane geometry
    const int wid  = tid >> 6, lane = tid & 63;
    const int g    = lane >> 4;      // channel group: channels 4g..4g+3
    const int p    = lane & 15;      // pixel slot 0..15
    const int c    = (wid & 3) * 16 + p;
    const int band = wid >> 2;
    const int rb0  = band * 12;      // conv-window top LDS row for j=0

    // stage v (non-FIRST) rows 1..48 <- vg image rows vlo..vlo+47
    if (!FIRST) {
        for (int i = tid; i < 48 * 64; i += NT) {
            const int L = (i >> 6) + 1, col = i & 63;
            va[L * PW + col + 1] = vg[b * 4096 + (vlo + L - 1) * 64 + col];
        }
    }

    // rq[cc*12+j] = conv3x3(r, q_w[4g+cc]) at (row 1+rb0+j, col c); v0 if FIRST
    float wq[36];
    #pragma unroll
    for (int t = 0; t < 36; ++t) wq[t] = q_w[g * 36 + t];

    float rq[48];
    {
        const float* rw = r_s + rb0 * PW + c;
        float a0[3], a1[3], a2[3];
        #pragma unroll
        for (int d = 0; d < 3; ++d) { a0[d] = rw[d]; a1[d] = rw[PW + d]; }
        #pragma unroll
        for (int j = 0; j < 12; ++j) {
            #pragma unroll
            for (int d = 0; d < 3; ++d) a2[d] = rw[(j + 2) * PW + d];
            #pragma unroll
            for (int cc = 0; cc < 4; ++cc) {
                float a = 0.f;
                #pragma unroll
                for (int d = 0; d < 3; ++d) {
                    a = fmaf(wq[cc * 9 + d],     a0[d], a);
                    a = fmaf(wq[cc * 9 + 3 + d], a1[d], a);
                    a = fmaf(wq[cc * 9 + 6 + d], a2[d], a);
                }
                rq[cc * 12 + j] = a;
            }
            if (FIRST) {
                float m = fmaxf(fmaxf(rq[0 * 12 + j], rq[1 * 12 + j]),
                                fmaxf(rq[2 * 12 + j], rq[3 * 12 + j]));
                m = fmaxf(m, __shfl_xor(m, 16));
                m = fmaxf(m, __shfl_xor(m, 32));
                if (g == 0) va[(1 + rb0 + j) * PW + c + 1] = m;
            }
            #pragma unroll
            for (int d = 0; d < 3; ++d) { a0[d] = a1[d]; a1[d] = a2[d]; }
        }
    }

    float wv[36];
    #pragma unroll
    for (int t = 0; t < 36; ++t) wv[t] = w[g * 36 + t];
    __syncthreads();  // B4: v0 / staged v ready

    // NIT sweeps
    float* vcur = va;
    float* vnxt = vb;
    #pragma unroll 1
    for (int it = 0; it < NIT; ++it) {
        const float* vw = vcur + rb0 * PW + c;
        float a0[3], a1[3], a2[3];
        #pragma unroll
        for (int d = 0; d < 3; ++d) { a0[d] = vw[d]; a1[d] = vw[PW + d]; }
        #pragma unroll
        for (int j = 0; j < 12; ++j) {
            #pragma unroll
            for (int d = 0; d < 3; ++d) a2[d] = vw[(j + 2) * PW + d];
            float q0 = rq[0 * 12 + j], q1 = rq[1 * 12 + j];
            float q2 = rq[2 * 12 + j], q3 = rq[3 * 12 + j];
            #pragma unroll
            for (int d = 0; d < 3; ++d) {
                q0 = fmaf(wv[0 + d],  a0[d], q0); q0 = fmaf(wv[3 + d],  a1[d], q0); q0 = fmaf(wv[6 + d],  a2[d], q0);
                q1 = fmaf(wv[9 + d],  a0[d], q1); q1 = fmaf(wv[12 + d], a1[d], q1); q1 = fmaf(wv[15 + d], a2[d], q1);
                q2 = fmaf(wv[18 + d], a0[d], q2); q2 = fmaf(wv[21 + d], a1[d], q2); q2 = fmaf(wv[24 + d], a2[d], q2);
                q3 = fmaf(wv[27 + d], a0[d], q3); q3 = fmaf(wv[30 + d], a1[d], q3); q3 = fmaf(wv[33 + d], a2[d], q3);
            }
            float m = fmaxf(fmaxf(q0, q1), fmaxf(q2, q3));
            m = fmaxf(m, __shfl_xor(m, 16));
            m = fmaxf(m, __shfl_xor(m, 32));
            if (g == 0) vnxt[(1 + rb0 + j) * PW + c + 1] = m;
            #pragma unroll
            for (int d = 0; d < 3; ++d) { a0[d] = a1[d]; a1[d] = a2[d]; }
        }
        __syncthreads();
        float* t = vcur; vcur = vnxt; vnxt = t;
    }

    // writeback core rows (image half*32 .. half*32+31; L = ir - vlo + 1)
    if (!LAST) {
        for (int i = tid; i < 32 * 64; i += NT) {
            const int ir = half * 32 + (i >> 6), col = i & 63;
            vg[b * 4096 + ir * 64 + col] = vcur[(ir - vlo + 1) * PW + col + 1];
        }
    } else {
        float* out_v = out + 1024 + (size_t)b * 4096;
        for (int i = tid; i < 32 * 64; i += NT) {
            const int ir = half * 32 + (i >> 6), col = i & 63;
            out_v[ir * 64 + col] = vcur[(ir - vlo + 1) * PW + col + 1];
        }
    }
    if (FIRST) {
        float* out_r = out + 1024 + (size_t)128 * 4096 + (size_t)b * 4096;
        float* out_h = out + 1024 + (size_t)256 * 4096 + (size_t)b * 4096;
        for (int i = tid; i < 32 * 64; i += NT) {
            const int ir = half * 32 + (i >> 6), col = i & 63;
            out_r[ir * 64 + col] = r_s[(ir - vlo + 1) * PW + col + 1];
            out_h[ir * 64 + col] = X2[ir * 64 + col];
        }
    }

    if (LAST) {
        const int s1 = S1[b], s2 = S2[b];
        if ((s1 >> 5) == half && tid == 0) {
            float q16[16];
            #pragma unroll
            for (int o = 0; o < 16; ++o) {
                float acc = 0.f;
                #pragma unroll
                for (int dy = 0; dy < 3; ++dy)
                    #pragma unroll
                    for (int dx = 0; dx < 3; ++dx) {
                        const int li = (s1 + dy - vlo) * PW + s2 + dx;
                        acc = fmaf(q_w[o * 9 + dy * 3 + dx], r_s[li], acc);
                        acc = fmaf(w[o * 9 + dy * 3 + dx],  vcur[li], acc);
                    }
                q16[o] = acc;
            }
            float lg[4];
            #pragma unroll
            for (int j = 0; j < 4; ++j) {
                float a = 0.f;
                #pragma unroll
                for (int o = 0; o < 16; ++o) a = fmaf(fc_w[j * 16 + o], q16[o], a);
                lg[j] = a;
            }
            const float m  = fmaxf(fmaxf(lg[0], lg[1]), fmaxf(lg[2], lg[3]));
            const float e0 = expf(lg[0] - m), e1 = expf(lg[1] - m);
            const float e2 = expf(lg[2] - m), e3 = expf(lg[3] - m);
            const float s  = e0 + e1 + e2 + e3;
            out[b * 4 + 0] = lg[0]; out[b * 4 + 1] = lg[1];
            out[b * 4 + 2] = lg[2]; out[b * 4 + 3] = lg[3];
            out[512 + b * 4 + 0] = e0 / s; out[512 + b * 4 + 1] = e1 / s;
            out[512 + b * 4 + 2] = e2 / s; out[512 + b * 4 + 3] = e3 / s;
        }
    }
}

extern "C" void kernel_launch(void* const* d_in, const int* in_sizes, int n_in,
                              void* d_out, int out_size, void* d_ws, size_t ws_size,
                              hipStream_t stream) {
    const float* layout  = (const float*)d_in[0];
    const float* heatmap = (const float*)d_in[1];
    const float* h_w     = (const float*)d_in[2];
    const float* h_b     = (const float*)d_in[3];
    const float* r_w     = (const float*)d_in[4];
    const float* q_w     = (const float*)d_in[5];
    const float* w       = (const float*)d_in[6];
    const float* fc_w    = (const float*)d_in[7];
    const int*   S1      = (const int*)d_in[8];
    const int*   S2      = (const int*)d_in[9];
    float* out = (float*)d_out;
    float* vg  = (float*)d_ws;   // 128*4096 f32 = 2 MB

    hipLaunchKernelGGL((vin_chunk<15, true,  false>), dim3(256), dim3(NT), 0, stream,
                       layout, heatmap, h_w, h_b, r_w, q_w, w, fc_w, S1, S2, vg, out);
    hipLaunchKernelGGL((vin_chunk<14, false, true>),  dim3(256), dim3(NT), 0, stream,
                       layout, heatmap, h_w, h_b, r_w, q_w, w, fc_w, S1, S2, vg, out);
}

// Round 8
// 116.358 us; speedup vs baseline: 1.0339x; 1.0025x over previous
//
#include <hip/hip_runtime.h>
#include <math.h>

#define NT 1024
#define PW 66      // padded LDS row stride
#define RR 52      // LDS buffer rows (52 X rows / 50 r rows / 48 v rows + ring)

// Two launches: chunk<15,FIRST> then chunk<14,LAST>. 256 blocks (1 per CU),
// block = half image (32 core rows + 16-row internal halo).
// Wave = 16 pixel-cols x 4 channel-groups: lane: g = lane>>4 (channels 4g..4g+3),
// p = lane&15, col c=(wid&3)*16+p, rows band*12..band*12+11 (band = wid>>2).
//
// amdgpu_waves_per_eu(4,4): grid==256==#CUs so only 16 waves/CU are ever
// resident (4/EU). Pinning the occupancy target to exactly 4 waves/EU gives
// the register allocator the full 512/4 = 128-VGPR budget, keeping wv[36] +
// rq[48] + the sliding window in arch VGPRs. (Default heuristic targeted the
// LDS-derived 2 blocks/CU = 8 waves/EU -> 64-VGPR cap -> AGPR shuttling,
// ~58% of VALU issue was accvgpr_read/write; VGPR_Count was stuck at 64
// in rounds 2-7 regardless of __launch_bounds__.)
template<int NIT, bool FIRST, bool LAST>
__global__ __launch_bounds__(NT)
__attribute__((amdgpu_waves_per_eu(4, 4)))
void vin_chunk(const float* __restrict__ layout,
               const float* __restrict__ heatmap,
               const float* __restrict__ h_w,
               const float* __restrict__ h_b,
               const float* __restrict__ r_w,
               const float* __restrict__ q_w,
               const float* __restrict__ w,
               const float* __restrict__ fc_w,
               const int* __restrict__ S1,
               const int* __restrict__ S2,
               float* __restrict__ vg,
               float* __restrict__ out)
{
    __shared__ float rh[28];
    __shared__ float r_s[RR * PW];   // X0, then r   (r_s row M <-> image row vlo-1+M)
    __shared__ float va[RR * PW];    // X1, then v ping (v row L <-> image row vlo+L-1)
    __shared__ float vb[RR * PW];    // X2, then v pong

    const int b2   = blockIdx.x;
    const int b    = b2 >> 1;
    const int half = b2 & 1;
    const int vlo  = half ? 16 : 0;
    const int tid  = threadIdx.x;

    // B0: zero everything (borders must be 0)
    for (int i = tid; i < RR * PW; i += NT) { r_s[i] = 0.f; va[i] = 0.f; vb[i] = 0.f; }
    __syncthreads();

    // collapse 150-ch h-conv + 1x1 r-conv into 28 coeffs (32 threads per coeff)
    if (tid < 896) {
        const int coeff = tid >> 5, j = tid & 31;
        float s = 0.f;
        for (int c = j; c < 150; c += 32)
            s += r_w[c] * ((coeff < 27) ? h_w[c * 27 + coeff] : h_b[c]);
        s += __shfl_xor(s, 1, 32);  s += __shfl_xor(s, 2, 32);
        s += __shfl_xor(s, 4, 32);  s += __shfl_xor(s, 8, 32);
        s += __shfl_xor(s, 16, 32);
        if (j == 0) rh[coeff] = s;
    }
    // stage X rows M=0..51 <-> image rows vlo-2..vlo+49 (zero OOB kept from memset)
    const float* X0 = layout  + (size_t)b * 2 * 4096;
    const float* X1 = X0 + 4096;
    const float* X2 = heatmap + (size_t)b * 4096;
    for (int i = tid; i < RR * 64; i += NT) {
        const int M = i >> 6, col = i & 63;
        const int ir = vlo - 2 + M;
        if (ir >= 0 && ir < 64) {
            const int s = ir * 64 + col, d = M * PW + col + 1;
            r_s[d] = X0[s]; va[d] = X1[s]; vb[d] = X2[s];
        }
    }
    __syncthreads();  // B1: X + rh ready

    // r (rows 0..49, cols 0..63) into registers; window top X-row == dest r-row
    float rv[4];
    int   rpx[4];
    #pragma unroll
    for (int k2 = 0; k2 < 4; ++k2) {
        const int i = tid + k2 * NT;
        rpx[k2] = -1;
        if (i < 50 * 64) {
            const int row = i >> 6, col = i & 63;
            float acc = rh[27];
            #pragma unroll
            for (int dy = 0; dy < 3; ++dy)
                #pragma unroll
                for (int dx = 0; dx < 3; ++dx) {
                    const int idx = (row + dy) * PW + col + dx;
                    acc = fmaf(rh[0 * 9 + dy * 3 + dx], r_s[idx], acc);
                    acc = fmaf(rh[1 * 9 + dy * 3 + dx], va[idx],  acc);
                    acc = fmaf(rh[2 * 9 + dy * 3 + dx], vb[idx],  acc);
                }
            const int ir = vlo - 1 + row;
            rv[k2]  = (ir >= 0 && ir < 64) ? acc : 0.f;  // true zero padding
            rpx[k2] = row * PW + col + 1;
        }
    }
    __syncthreads();  // B2: X consumed

    // overwrite: r -> r_s, re-zero v buffers
    for (int i = tid; i < RR * PW; i += NT) { va[i] = 0.f; vb[i] = 0.f; }
    #pragma unroll
    for (int k2 = 0; k2 < 4; ++k2) if (rpx[k2] >= 0) r_s[rpx[k2]] = rv[k2];
    __syncthreads();  // B3: r ready, v buffers zero

    // per-lane geometry
    const int wid  = tid >> 6, lane = tid & 63;
    const int g    = lane >> 4;      // channel group: channels 4g..4g+3
    const int p    = lane & 15;      // pixel slot 0..15
    const int c    = (wid & 3) * 16 + p;
    const int band = wid >> 2;
    const int rb0  = band * 12;      // conv-window top LDS row for j=0

    // stage v (non-FIRST) rows 1..48 <- vg image rows vlo..vlo+47
    if (!FIRST) {
        for (int i = tid; i < 48 * 64; i += NT) {
            const int L = (i >> 6) + 1, col = i & 63;
            va[L * PW + col + 1] = vg[b * 4096 + (vlo + L - 1) * 64 + col];
        }
    }

    // rq[cc*12+j] = conv3x3(r, q_w[4g+cc]) at (row 1+rb0+j, col c); v0 if FIRST
    float wq[36];
    #pragma unroll
    for (int t = 0; t < 36; ++t) wq[t] = q_w[g * 36 + t];

    float rq[48];
    {
        const float* rw = r_s + rb0 * PW + c;
        float a0[3], a1[3], a2[3];
        #pragma unroll
        for (int d = 0; d < 3; ++d) { a0[d] = rw[d]; a1[d] = rw[PW + d]; }
        #pragma unroll
        for (int j = 0; j < 12; ++j) {
            #pragma unroll
            for (int d = 0; d < 3; ++d) a2[d] = rw[(j + 2) * PW + d];
            #pragma unroll
            for (int cc = 0; cc < 4; ++cc) {
                float a = 0.f;
                #pragma unroll
                for (int d = 0; d < 3; ++d) {
                    a = fmaf(wq[cc * 9 + d],     a0[d], a);
                    a = fmaf(wq[cc * 9 + 3 + d], a1[d], a);
                    a = fmaf(wq[cc * 9 + 6 + d], a2[d], a);
                }
                rq[cc * 12 + j] = a;
            }
            if (FIRST) {
                float m = fmaxf(fmaxf(rq[0 * 12 + j], rq[1 * 12 + j]),
                                fmaxf(rq[2 * 12 + j], rq[3 * 12 + j]));
                m = fmaxf(m, __shfl_xor(m, 16));
                m = fmaxf(m, __shfl_xor(m, 32));
                if (g == 0) va[(1 + rb0 + j) * PW + c + 1] = m;
            }
            #pragma unroll
            for (int d = 0; d < 3; ++d) { a0[d] = a1[d]; a1[d] = a2[d]; }
        }
    }

    float wv[36];
    #pragma unroll
    for (int t = 0; t < 36; ++t) wv[t] = w[g * 36 + t];
    __syncthreads();  // B4: v0 / staged v ready

    // NIT sweeps
    float* vcur = va;
    float* vnxt = vb;
    #pragma unroll 1
    for (int it = 0; it < NIT; ++it) {
        const float* vw = vcur + rb0 * PW + c;
        float a0[3], a1[3], a2[3];
        #pragma unroll
        for (int d = 0; d < 3; ++d) { a0[d] = vw[d]; a1[d] = vw[PW + d]; }
        #pragma unroll
        for (int j = 0; j < 12; ++j) {
            #pragma unroll
            for (int d = 0; d < 3; ++d) a2[d] = vw[(j + 2) * PW + d];
            float q0 = rq[0 * 12 + j], q1 = rq[1 * 12 + j];
            float q2 = rq[2 * 12 + j], q3 = rq[3 * 12 + j];
            #pragma unroll
            for (int d = 0; d < 3; ++d) {
                q0 = fmaf(wv[0 + d],  a0[d], q0); q0 = fmaf(wv[3 + d],  a1[d], q0); q0 = fmaf(wv[6 + d],  a2[d], q0);
                q1 = fmaf(wv[9 + d],  a0[d], q1); q1 = fmaf(wv[12 + d], a1[d], q1); q1 = fmaf(wv[15 + d], a2[d], q1);
                q2 = fmaf(wv[18 + d], a0[d], q2); q2 = fmaf(wv[21 + d], a1[d], q2); q2 = fmaf(wv[24 + d], a2[d], q2);
                q3 = fmaf(wv[27 + d], a0[d], q3); q3 = fmaf(wv[30 + d], a1[d], q3); q3 = fmaf(wv[33 + d], a2[d], q3);
            }
            float m = fmaxf(fmaxf(q0, q1), fmaxf(q2, q3));
            m = fmaxf(m, __shfl_xor(m, 16));
            m = fmaxf(m, __shfl_xor(m, 32));
            if (g == 0) vnxt[(1 + rb0 + j) * PW + c + 1] = m;
            #pragma unroll
            for (int d = 0; d < 3; ++d) { a0[d] = a1[d]; a1[d] = a2[d]; }
        }
        __syncthreads();
        float* t = vcur; vcur = vnxt; vnxt = t;
    }

    // writeback core rows (image half*32 .. half*32+31; L = ir - vlo + 1)
    if (!LAST) {
        for (int i = tid; i < 32 * 64; i += NT) {
            const int ir = half * 32 + (i >> 6), col = i & 63;
            vg[b * 4096 + ir * 64 + col] = vcur[(ir - vlo + 1) * PW + col + 1];
        }
    } else {
        float* out_v = out + 1024 + (size_t)b * 4096;
        for (int i = tid; i < 32 * 64; i += NT) {
            const int ir = half * 32 + (i >> 6), col = i & 63;
            out_v[ir * 64 + col] = vcur[(ir - vlo + 1) * PW + col + 1];
        }
    }
    if (FIRST) {
        float* out_r = out + 1024 + (size_t)128 * 4096 + (size_t)b * 4096;
        float* out_h = out + 1024 + (size_t)256 * 4096 + (size_t)b * 4096;
        for (int i = tid; i < 32 * 64; i += NT) {
            const int ir = half * 32 + (i >> 6), col = i & 63;
            out_r[ir * 64 + col] = r_s[(ir - vlo + 1) * PW + col + 1];
            out_h[ir * 64 + col] = X2[ir * 64 + col];
        }
    }

    if (LAST) {
        const int s1 = S1[b], s2 = S2[b];
        if ((s1 >> 5) == half && tid == 0) {
            float q16[16];
            #pragma unroll
            for (int o = 0; o < 16; ++o) {
                float acc = 0.f;
                #pragma unroll
                for (int dy = 0; dy < 3; ++dy)
                    #pragma unroll
                    for (int dx = 0; dx < 3; ++dx) {
                        const int li = (s1 + dy - vlo) * PW + s2 + dx;
                        acc = fmaf(q_w[o * 9 + dy * 3 + dx], r_s[li], acc);
                        acc = fmaf(w[o * 9 + dy * 3 + dx],  vcur[li], acc);
                    }
                q16[o] = acc;
            }
            float lg[4];
            #pragma unroll
            for (int j = 0; j < 4; ++j) {
                float a = 0.f;
                #pragma unroll
                for (int o = 0; o < 16; ++o) a = fmaf(fc_w[j * 16 + o], q16[o], a);
                lg[j] = a;
            }
            const float m  = fmaxf(fmaxf(lg[0], lg[1]), fmaxf(lg[2], lg[3]));
            const float e0 = expf(lg[0] - m), e1 = expf(lg[1] - m);
            const float e2 = expf(lg[2] - m), e3 = expf(lg[3] - m);
            const float s  = e0 + e1 + e2 + e3;
            out[b * 4 + 0] = lg[0]; out[b * 4 + 1] = lg[1];
            out[b * 4 + 2] = lg[2]; out[b * 4 + 3] = lg[3];
            out[512 + b * 4 + 0] = e0 / s; out[512 + b * 4 + 1] = e1 / s;
            out[512 + b * 4 + 2] = e2 / s; out[512 + b * 4 + 3] = e3 / s;
        }
    }
}

extern "C" void kernel_launch(void* const* d_in, const int* in_sizes, int n_in,
                              void* d_out, int out_size, void* d_ws, size_t ws_size,
                              hipStream_t stream) {
    const float* layout  = (const float*)d_in[0];
    const float* heatmap = (const float*)d_in[1];
    const float* h_w     = (const float*)d_in[2];
    const float* h_b     = (const float*)d_in[3];
    const float* r_w     = (const float*)d_in[4];
    const float* q_w     = (const float*)d_in[5];
    const float* w       = (const float*)d_in[6];
    const float* fc_w    = (const float*)d_in[7];
    const int*   S1      = (const int*)d_in[8];
    const int*   S2      = (const int*)d_in[9];
    float* out = (float*)d_out;
    float* vg  = (float*)d_ws;   // 128*4096 f32 = 2 MB

    hipLaunchKernelGGL((vin_chunk<15, true,  false>), dim3(256), dim3(NT), 0, stream,
                       layout, heatmap, h_w, h_b, r_w, q_w, w, fc_w, S1, S2, vg, out);
    hipLaunchKernelGGL((vin_chunk<14, false, true>),  dim3(256), dim3(NT), 0, stream,
                       layout, heatmap, h_w, h_b, r_w, q_w, w, fc_w, S1, S2, vg, out);
}